// Round 4
// baseline (186.297 us; speedup 1.0000x reference)
//
#include <hip/hip_runtime.h>

#define NROWS 8192
#define DDIM  512
#define INV_TAU 14.285714285714286f

typedef short short8 __attribute__((ext_vector_type(8)));
typedef float f32x4 __attribute__((ext_vector_type(4)));

__device__ static inline float bf2f(unsigned short u) {
  return __uint_as_float(((unsigned int)u) << 16);
}
__device__ static inline unsigned short f2bf(float f) {
  unsigned int u = __float_as_uint(f);
  u += 0x7fffu + ((u >> 16) & 1u);   // round-to-nearest-even
  return (unsigned short)(u >> 16);
}

__device__ static inline void load_lds16(const void* g, void* l) {
  __builtin_amdgcn_global_load_lds(
      (const __attribute__((address_space(1))) void*)g,
      (__attribute__((address_space(3))) void*)l, 16, 0, 0);
}

// ---------------- normalize: fp32 rows -> bf16 normalized rows ----------------
__global__ __launch_bounds__(256) void norm_kernel(
    const float* __restrict__ zi, const float* __restrict__ zj,
    unsigned short* __restrict__ ziN, unsigned short* __restrict__ zjN) {
  int rid = blockIdx.x * 4 + (threadIdx.x >> 6);   // 0..16383
  int lane = threadIdx.x & 63;
  const float* src;
  unsigned short* dst;
  if (rid < NROWS) { src = zi + (size_t)rid * DDIM; dst = ziN + (size_t)rid * DDIM; }
  else             { src = zj + (size_t)(rid - NROWS) * DDIM; dst = zjN + (size_t)(rid - NROWS) * DDIM; }
  float4 v0 = *(const float4*)(src + lane * 4);
  float4 v1 = *(const float4*)(src + 256 + lane * 4);
  float ss = v0.x*v0.x + v0.y*v0.y + v0.z*v0.z + v0.w*v0.w
           + v1.x*v1.x + v1.y*v1.y + v1.z*v1.z + v1.w*v1.w;
  #pragma unroll
  for (int off = 1; off < 64; off <<= 1) ss += __shfl_xor(ss, off);
  float scale = 1.0f / fmaxf(sqrtf(ss), 1e-8f);
  ushort4 o0, o1;
  o0.x = f2bf(v0.x*scale); o0.y = f2bf(v0.y*scale); o0.z = f2bf(v0.z*scale); o0.w = f2bf(v0.w*scale);
  o1.x = f2bf(v1.x*scale); o1.y = f2bf(v1.y*scale); o1.z = f2bf(v1.z*scale); o1.w = f2bf(v1.w*scale);
  *(ushort4*)(dst + lane * 4) = o0;
  *(ushort4*)(dst + 256 + lane * 4) = o1;
}

// ---------------- zero row/col accumulators (contiguous 16384 floats) --------
__global__ __launch_bounds__(256) void zero_kernel(float* __restrict__ p) {
  p[blockIdx.x * 256 + threadIdx.x] = 0.0f;
}

// ---------------- pos[i] = dot(ziN[i], zjN[i]) / tau --------------------------
__global__ __launch_bounds__(256) void pos_kernel(
    const unsigned short* __restrict__ ziN, const unsigned short* __restrict__ zjN,
    float* __restrict__ pos) {
  int row = blockIdx.x * 4 + (threadIdx.x >> 6);
  int lane = threadIdx.x & 63;
  const unsigned short* a = ziN + (size_t)row * DDIM;
  const unsigned short* b = zjN + (size_t)row * DDIM;
  ushort4 a0 = *(const ushort4*)(a + lane * 4);
  ushort4 a1 = *(const ushort4*)(a + 256 + lane * 4);
  ushort4 b0 = *(const ushort4*)(b + lane * 4);
  ushort4 b1 = *(const ushort4*)(b + 256 + lane * 4);
  float s = bf2f(a0.x)*bf2f(b0.x) + bf2f(a0.y)*bf2f(b0.y)
          + bf2f(a0.z)*bf2f(b0.z) + bf2f(a0.w)*bf2f(b0.w)
          + bf2f(a1.x)*bf2f(b1.x) + bf2f(a1.y)*bf2f(b1.y)
          + bf2f(a1.z)*bf2f(b1.z) + bf2f(a1.w)*bf2f(b1.w);
  #pragma unroll
  for (int off = 1; off < 64; off <<= 1) s += __shfl_xor(s, off);
  if (lane == 0) pos[row] = s * INV_TAU;
}

// ---------------- fused sim GEMM + exp + row/col sum --------------------------
// grid 16x16 (1 block/CU). 512x512 per block = 4 serpentine 256^2 sub-tiles,
// continuous 64-tile virtual-K pipeline, BK=32, 4-slot LDS rotation, stage+3.
// Phase engine: frag prefetch one phase deep, compiler-counted lgkm waits,
// vmcnt(4) once per pair, 3 raw barriers per pair.
__global__ __launch_bounds__(512, 2) void sim_kernel(
    const unsigned short* __restrict__ ziN, const unsigned short* __restrict__ zjN,
    float* __restrict__ row_sum, float* __restrict__ col_sum) {
  __shared__ unsigned short lds[65536];   // 128 KiB = 4 slots x 32KB
  const int tid  = threadIdx.x;
  const int lane = tid & 63;
  const int wid  = tid >> 6;
  const int wr   = wid >> 2;        // 0..1  (m-half: 128 rows of sub-tile)
  const int wc   = wid & 3;         // 0..3  (n-quarter: 64 cols)
  const int fr   = lane & 15;
  const int g    = lane >> 4;
  const int by   = blockIdx.y, bx = blockIdx.x;

  // staging thread-consts: wave w stages slab w of a 128-row half
  const int rowoff = wid * 16 + fr;       // 0..127
  const int koff   = g * 8;               // 0,8,16,24

  f32x4 acc[8][4] = {};
  short8 afA[4], afB[4], bf[4];

  auto stage_half = [&](const unsigned short* __restrict__ base, int growbase,
                        int kt3, int dstoff) {
    load_lds16(base + (size_t)(growbase + rowoff) * DDIM + kt3 * 32 + koff,
               (char*)lds + dstoff + tid * 16);
  };

  // thread-const byte offsets of ds_read addresses
  const int ard = wr * 8192 + g * 256 + fr * 16;          // + slot + m*1024
  const int brd = 16384 + wc * 4096 + g * 256 + fr * 16;  // + slot + n*1024

#define MFMA_HALF(AF, OFF)                                                 \
  __builtin_amdgcn_s_setprio(1);                                           \
  _Pragma("unroll")                                                        \
  for (int m = 0; m < 4; ++m) {                                            \
    _Pragma("unroll")                                                      \
    for (int n = 0; n < 4; ++n)                                            \
      acc[OFF + m][n] = __builtin_amdgcn_mfma_f32_16x16x32_bf16(           \
          AF[m], bf[n], acc[OFF + m][n], 0, 0, 0);                         \
  }                                                                        \
  __builtin_amdgcn_s_setprio(0);

#define PAIR_BODY(P) do {                                                  \
    const int _p = (P);                                                    \
    const int _slot  = (_p & 3) * 32768;                                   \
    const int _slotn = ((_p + 1) & 3) * 32768;                             \
    const bool _stg = (_p <= 60);                                          \
    int _kt3 = 0, _br3 = 0, _bc3 = 0, _sl3 = 0;                            \
    if (_stg) {                                                            \
      const int _t3 = _p + 3, _s3 = _t3 >> 4;                              \
      _kt3 = _t3 & 15;                                                     \
      _br3 = by * 512 + (_s3 >> 1) * 256;                                  \
      _bc3 = bx * 512 + ((_s3 & 1) ^ (_s3 >> 1)) * 256;                    \
      _sl3 = (_t3 & 3) * 32768;                                            \
    }                                                                      \
    /* ---- phase 0: prefetch afB (this pair m4..7), stage A(p+3) */       \
    _Pragma("unroll")                                                      \
    for (int m = 0; m < 4; ++m)                                            \
      afB[m] = *(const short8*)((const char*)lds + _slot + ard + (m + 4) * 1024); \
    if (_stg) {                                                            \
      stage_half(ziN, _br3,       _kt3, _sl3);                             \
      stage_half(ziN, _br3 + 128, _kt3, _sl3 + 8192);                      \
    }                                                                      \
    if (_p < 62) asm volatile("s_waitcnt vmcnt(4)" ::: "memory");          \
    else         asm volatile("s_waitcnt vmcnt(0)" ::: "memory");          \
    __builtin_amdgcn_s_barrier();                                          \
    MFMA_HALF(afA, 0)                                                      \
    /* ---- phase 1: prefetch next pair's afA, stage B(p+3) */             \
    if (_p < 63) {                                                         \
      _Pragma("unroll")                                                    \
      for (int m = 0; m < 4; ++m)                                          \
        afA[m] = *(const short8*)((const char*)lds + _slotn + ard + m * 1024); \
    }                                                                      \
    if (_stg) {                                                            \
      stage_half(zjN, _bc3,       _kt3, _sl3 + 16384);                     \
      stage_half(zjN, _bc3 + 128, _kt3, _sl3 + 16384 + 8192);              \
    }                                                                      \
    __builtin_amdgcn_s_barrier();                                          \
    MFMA_HALF(afB, 4)                                                      \
    /* next pair's B frags (single bf buffer: read after last use) */      \
    if (_p < 63) {                                                         \
      _Pragma("unroll")                                                    \
      for (int n = 0; n < 4; ++n)                                          \
        bf[n] = *(const short8*)((const char*)lds + _slotn + brd + n * 1024); \
    }                                                                      \
    __builtin_amdgcn_s_barrier();                                          \
  } while (0)

  const float Cc = INV_TAU * 1.4426950408889634f;
  auto epi = [&](int s) {
    const int brow_s = by * 512 + (s >> 1) * 256;
    const int bcol_s = bx * 512 + ((s & 1) ^ (s >> 1)) * 256;
    const int r0 = brow_s + wr * 128 + g * 4;   // + m*16 + r
    const int c0 = bcol_s + wc * 64 + fr;       // + n*16
    #pragma unroll
    for (int m = 0; m < 8; ++m)
      #pragma unroll
      for (int n = 0; n < 4; ++n)
        #pragma unroll
        for (int r = 0; r < 4; ++r) {
          int gi = r0 + m * 16 + r;
          int gj = c0 + n * 16;
          float e = exp2f((acc[m][n][r] - 1.0f) * Cc);
          acc[m][n][r] = (gi == gj) ? 0.0f : e;
        }
    #pragma unroll
    for (int n = 0; n < 4; ++n) {
      float cs = 0.0f;
      #pragma unroll
      for (int m = 0; m < 8; ++m)
        #pragma unroll
        for (int r = 0; r < 4; ++r) cs += acc[m][n][r];
      cs += __shfl_xor(cs, 16);
      cs += __shfl_xor(cs, 32);
      if (lane < 16) atomicAdd(&col_sum[c0 + n * 16], cs);
    }
    #pragma unroll
    for (int m = 0; m < 8; ++m)
      #pragma unroll
      for (int r = 0; r < 4; ++r) {
        float rs = acc[m][0][r] + acc[m][1][r] + acc[m][2][r] + acc[m][3][r];
        rs += __shfl_xor(rs, 1);
        rs += __shfl_xor(rs, 2);
        rs += __shfl_xor(rs, 4);
        rs += __shfl_xor(rs, 8);
        if (fr == 0) atomicAdd(&row_sum[r0 + m * 16 + r], rs);
      }
    #pragma unroll
    for (int m = 0; m < 8; ++m)
      #pragma unroll
      for (int n = 0; n < 4; ++n) acc[m][n] = (f32x4){0.f, 0.f, 0.f, 0.f};
  };

  // ---- prologue: stage K-tiles 0,1,2 (sub-tile 0), keep tiles 1,2 in flight
  #pragma unroll
  for (int v = 0; v < 3; ++v) {
    const int sl = v * 32768;
    stage_half(ziN, by * 512,       v, sl);
    stage_half(ziN, by * 512 + 128, v, sl + 8192);
    stage_half(zjN, bx * 512,       v, sl + 16384);
    stage_half(zjN, bx * 512 + 128, v, sl + 16384 + 8192);
  }
  asm volatile("s_waitcnt vmcnt(8)" ::: "memory");
  __builtin_amdgcn_s_barrier();
  // prime pair-0 fragments
  #pragma unroll
  for (int n = 0; n < 4; ++n)
    bf[n] = *(const short8*)((const char*)lds + brd + n * 1024);
  #pragma unroll
  for (int m = 0; m < 4; ++m)
    afA[m] = *(const short8*)((const char*)lds + ard + m * 1024);

  // ---- main loop: 64 virtual K-tiles = 32 pairs of pairs
  #pragma unroll 2
  for (int pp = 0; pp < 32; ++pp) {
    const int p0 = 2 * pp, p1 = 2 * pp + 1;
    PAIR_BODY(p0);
    PAIR_BODY(p1);
    if ((p1 & 15) == 15) epi(p1 >> 4);
  }
}

// ---------------- finalize: 3 scalars ----------------------------------------
__global__ __launch_bounds__(256) void finalize_kernel(
    const float* __restrict__ row_sum, const float* __restrict__ col_sum,
    const float* __restrict__ pos, float* __restrict__ out) {
  __shared__ float sA[4], sB[4];
  float sa = 0.0f, sb = 0.0f;
  for (int i = threadIdx.x; i < NROWS; i += 256) {
    float p = pos[i];
    sa += (INV_TAU + __logf(row_sum[i])) - p;
    sb += (INV_TAU + __logf(col_sum[i])) - p;
  }
  #pragma unroll
  for (int off = 1; off < 64; off <<= 1) {
    sa += __shfl_xor(sa, off);
    sb += __shfl_xor(sb, off);
  }
  if ((threadIdx.x & 63) == 0) { sA[threadIdx.x >> 6] = sa; sB[threadIdx.x >> 6] = sb; }
  __syncthreads();
  if (threadIdx.x == 0) {
    float ta = sA[0] + sA[1] + sA[2] + sA[3];
    float tb = sB[0] + sB[1] + sB[2] + sB[3];
    float e2t = ta / (float)NROWS;
    float t2e = tb / (float)NROWS;
    out[0] = 0.5f * (e2t + t2e);
    out[1] = e2t;
    out[2] = t2e;
  }
}

extern "C" void kernel_launch(void* const* d_in, const int* in_sizes, int n_in,
                              void* d_out, int out_size, void* d_ws, size_t ws_size,
                              hipStream_t stream) {
  const float* z_i = (const float*)d_in[0];
  const float* z_j = (const float*)d_in[1];
  float* out = (float*)d_out;
  char* ws = (char*)d_ws;
  unsigned short* ziN = (unsigned short*)ws;                       // 8 MB
  unsigned short* zjN = (unsigned short*)(ws + 8388608);           // 8 MB
  float* row_sum = (float*)(ws + 16777216);                        // 32 KB
  float* col_sum = row_sum + NROWS;                                // 32 KB (contiguous)
  float* pos     = col_sum + NROWS;                                // 32 KB

  norm_kernel<<<4096, 256, 0, stream>>>(z_i, z_j, ziN, zjN);
  zero_kernel<<<64, 256, 0, stream>>>(row_sum);                    // zeros row+col (contiguous)
  pos_kernel<<<2048, 256, 0, stream>>>(ziN, zjN, pos);
  dim3 grid(16, 16);
  sim_kernel<<<grid, 512, 0, stream>>>(ziN, zjN, row_sum, col_sum);
  finalize_kernel<<<1, 256, 0, stream>>>(row_sum, col_sum, pos, out);
}